// Round 2
// baseline (803.184 us; speedup 1.0000x reference)
//
#include <hip/hip_runtime.h>
#include <math.h>

#define N_NODES 100000
#define N_EDGES 3200000
#define NODE_F  128
#define EDGE_F  16
#define OUT_C   15

// ---------------------------------------------------------------------------
// Kernel 1: xw = x @ W_node   ([N,128] @ [128,15] -> [N,15])
// One thread per node. W_node staged in LDS (7.68 KB), broadcast reads.
// Per-lane float4 row reads; lines are L1-resident across the k-loop.
// ---------------------------------------------------------------------------
__global__ __launch_bounds__(256) void node_proj_kernel(
    const float* __restrict__ x, const float* __restrict__ wn,
    float* __restrict__ xw)
{
    __shared__ float wl[NODE_F * OUT_C];  // 1920 floats
    const int tid = threadIdx.x;
    for (int i = tid; i < NODE_F * OUT_C; i += 256) wl[i] = wn[i];
    __syncthreads();

    const int n = blockIdx.x * 256 + tid;
    if (n >= N_NODES) return;

    float acc[OUT_C];
#pragma unroll
    for (int c = 0; c < OUT_C; ++c) acc[c] = 0.f;

    const float4* xr = (const float4*)(x + (size_t)n * NODE_F);
#pragma unroll 4
    for (int k4 = 0; k4 < NODE_F / 4; ++k4) {
        float4 v = xr[k4];
        const float* vp = &v.x;
#pragma unroll
        for (int j = 0; j < 4; ++j) {
            const float xv = vp[j];
            const int k = k4 * 4 + j;
#pragma unroll
            for (int c = 0; c < OUT_C; ++c)
                acc[c] = fmaf(xv, wl[k * OUT_C + c], acc[c]);
        }
    }

    float* out = xw + (size_t)n * OUT_C;
#pragma unroll
    for (int c = 0; c < OUT_C; ++c) out[c] = acc[c];
}

// ---------------------------------------------------------------------------
// Kernel 2: axw[row] += adj[e] * xw[col]   (segment_sum via atomics)
// 16 lanes per edge (lane 15 idle): lane c handles output column c.
// xw (6 MB) stays L2/L3 resident; per-edge streams use nontemporal loads.
// ---------------------------------------------------------------------------
__global__ __launch_bounds__(256) void edge_scatter_kernel(
    const int* __restrict__ rows, const int* __restrict__ cols,
    const float* __restrict__ adj, const float* __restrict__ xw,
    float* __restrict__ axw)
{
    const int gid = blockIdx.x * 256 + threadIdx.x;
    const int e = gid >> 4;
    const int c = gid & 15;
    if (c >= OUT_C) return;   // e < N_EDGES guaranteed by exact grid

    const int r  = __builtin_nontemporal_load(rows + e);
    const int cl = __builtin_nontemporal_load(cols + e);
    const float a = __builtin_nontemporal_load(adj + e);
    const float v = a * xw[(size_t)cl * OUT_C + c];
    atomicAdd(&axw[(size_t)r * OUT_C + c], v);
}

// ---------------------------------------------------------------------------
// Kernel 3 (fused): ew = edge_attr @ W_edge ; score = sigmoid(<axw[r]*ew*axw[c]>)
// One thread per edge. W_edge (240 floats) in LDS. Avoids re-reading ew (192MB).
// ---------------------------------------------------------------------------
__global__ __launch_bounds__(256) void edge_fused_kernel(
    const int* __restrict__ rows, const int* __restrict__ cols,
    const float* __restrict__ ea, const float* __restrict__ we,
    const float* __restrict__ axw,
    float* __restrict__ ew_out, float* __restrict__ scores)
{
    __shared__ float ws[EDGE_F * OUT_C];  // 240 floats
    if (threadIdx.x < EDGE_F * OUT_C) ws[threadIdx.x] = we[threadIdx.x];
    __syncthreads();

    const int e = blockIdx.x * 256 + threadIdx.x;
    if (e >= N_EDGES) return;

    // load edge_attr row (16 floats, 64B)
    const float4* ear = (const float4*)(ea + (size_t)e * EDGE_F);
    float av[EDGE_F];
#pragma unroll
    for (int j = 0; j < 4; ++j) {
        float4 v = ear[j];
        av[4 * j + 0] = v.x; av[4 * j + 1] = v.y;
        av[4 * j + 2] = v.z; av[4 * j + 3] = v.w;
    }

    float ew[OUT_C];
#pragma unroll
    for (int c = 0; c < OUT_C; ++c) ew[c] = 0.f;
#pragma unroll
    for (int k = 0; k < EDGE_F; ++k) {
        const float a = av[k];
#pragma unroll
        for (int c = 0; c < OUT_C; ++c)
            ew[c] = fmaf(a, ws[k * OUT_C + c], ew[c]);
    }

    // write ew
    float* ewp = ew_out + (size_t)e * OUT_C;
#pragma unroll
    for (int c = 0; c < OUT_C; ++c) ewp[c] = ew[c];

    // bilinear score (h/t gathers hit the 6 MB L2-resident axw)
    const int r  = rows[e];
    const int cl = cols[e];
    const float* h = axw + (size_t)r  * OUT_C;
    const float* t = axw + (size_t)cl * OUT_C;
    float s = 0.f;
#pragma unroll
    for (int c = 0; c < OUT_C; ++c)
        s += ew[c] * h[c] * t[c];

    scores[e] = 1.f / (1.f + expf(-s));
}

// ---------------------------------------------------------------------------
extern "C" void kernel_launch(void* const* d_in, const int* in_sizes, int n_in,
                              void* d_out, int out_size, void* d_ws, size_t ws_size,
                              hipStream_t stream) {
    const float* x    = (const float*)d_in[0];
    const int*   eidx = (const int*)d_in[1];     // [2,E]: rows then cols
    const float* ea   = (const float*)d_in[2];
    const float* wn   = (const float*)d_in[3];
    const float* we   = (const float*)d_in[4];
    const float* adj  = (const float*)d_in[5];

    const int* rows = eidx;
    const int* cols = eidx + N_EDGES;

    float* out    = (float*)d_out;
    float* axw    = out;                                      // [N,15]
    float* ew_out = out + (size_t)N_NODES * OUT_C;            // [E,15]
    float* scores = out + (size_t)N_NODES * OUT_C
                        + (size_t)N_EDGES * OUT_C;            // [E]

    float* xw = (float*)d_ws;                                 // [N,15] scratch

    // zero the axw accumulator region (harness poisons d_out with 0xAA)
    hipMemsetAsync(axw, 0, (size_t)N_NODES * OUT_C * sizeof(float), stream);

    // 1) xw = x @ W_node
    node_proj_kernel<<<(N_NODES + 255) / 256, 256, 0, stream>>>(x, wn, xw);

    // 2) axw = segment_sum(adj * xw[col], row)
    edge_scatter_kernel<<<(N_EDGES * 16) / 256, 256, 0, stream>>>(
        rows, cols, adj, xw, axw);

    // 3) ew + scores (fused)
    edge_fused_kernel<<<(N_EDGES + 255) / 256, 256, 0, stream>>>(
        rows, cols, ea, we, axw, ew_out, scores);
}